// Round 1
// baseline (4067.129 us; speedup 1.0000x reference)
//
#include <hip/hip_runtime.h>

#define BB 4
#define TT 2048
#define HH 128
#define VV 32000

typedef __attribute__((ext_vector_type(8))) _Float16 half8;
typedef __attribute__((ext_vector_type(4))) float floatx4;

// ---------------------------------------------------------------------------
// K1/K3: pre-activation GEMM.
//   out[row][j] = dot(src_row, Wih[j][:]) + b1[j] + b2[j]
//   src_row = emb[idx[row]] when idx != nullptr, else src[row]
// grid = B*T blocks, 128 threads (thread j computes one output).
// ---------------------------------------------------------------------------
__global__ void preact_kernel(const float* __restrict__ src,
                              const int* __restrict__ idx,
                              const float* __restrict__ Wih,
                              const float* __restrict__ b1,
                              const float* __restrict__ b2,
                              float* __restrict__ out) {
    __shared__ float xs[HH];
    int row = blockIdx.x;
    int j = threadIdx.x;
    const float* srow = idx ? (src + (long)idx[row] * HH) : (src + (long)row * HH);
    xs[j] = srow[j];
    __syncthreads();
    const float* wrow = Wih + j * HH;
    float a0 = 0.f, a1 = 0.f, a2 = 0.f, a3 = 0.f;
#pragma unroll
    for (int k = 0; k < HH; k += 4) {
        float4 w = *(const float4*)(wrow + k);
        a0 += w.x * xs[k + 0];
        a1 += w.y * xs[k + 1];
        a2 += w.z * xs[k + 2];
        a3 += w.w * xs[k + 3];
    }
    out[(long)row * HH + j] = (a0 + a1) + (a2 + a3) + b1[j] + b2[j];
}

// ---------------------------------------------------------------------------
// K2/K4: Elman recurrence for one layer. One block per batch (4 blocks),
// 512 threads. Thread (j, ks): j = wave*16 + (lane&15) in [0,128),
// ks = lane>>4 in [0,4). Each thread holds W_hh[j][ks*32..ks*32+32) in regs.
// Per step: partial dot from LDS h, butterfly reduce across ks (lanes 16,32
// apart -> same wave), tanh, write back to LDS + global out.
// ---------------------------------------------------------------------------
__global__ void __launch_bounds__(512) rnn_kernel(
        const float* __restrict__ pre,   // [B,T,H] precomputed x@Wih^T + b_ih + b_hh
        const float* __restrict__ Whh,   // [H,H]
        const float* __restrict__ h0,    // [B,H]
        float* __restrict__ out,         // [B,T,H]
        float* __restrict__ hlast) {     // [B,H]
    __shared__ float hs[HH];
    const int b = blockIdx.x;
    const int tid = threadIdx.x;
    const int w = tid >> 6;
    const int l = tid & 63;
    const int j = w * 16 + (l & 15);
    const int ks = l >> 4;

    // Load this thread's W_hh chunk into registers.
    float wr[32];
    const float* wsrc = Whh + j * HH + ks * 32;
#pragma unroll
    for (int i = 0; i < 8; i++) {
        float4 v = *(const float4*)(wsrc + i * 4);
        wr[i * 4 + 0] = v.x;
        wr[i * 4 + 1] = v.y;
        wr[i * 4 + 2] = v.z;
        wr[i * 4 + 3] = v.w;
    }
    if (tid < HH) hs[tid] = h0[b * HH + tid];
    __syncthreads();

    const float* prow = pre + (long)b * TT * HH;
    float pnext = prow[j];  // prefetch t=0
    float hn = 0.f;
    for (int t = 0; t < TT; t++) {
        float p = pnext;
        if (t + 1 < TT) pnext = prow[(long)(t + 1) * HH + j];  // prefetch next step
        float a0 = 0.f, a1 = 0.f, a2 = 0.f, a3 = 0.f;
#pragma unroll
        for (int i = 0; i < 8; i++) {
            float4 h4 = *(const float4*)(&hs[ks * 32 + i * 4]);
            a0 += h4.x * wr[i * 4 + 0];
            a1 += h4.y * wr[i * 4 + 1];
            a2 += h4.z * wr[i * 4 + 2];
            a3 += h4.w * wr[i * 4 + 3];
        }
        float acc = (a0 + a1) + (a2 + a3);
        acc += __shfl_xor(acc, 16);
        acc += __shfl_xor(acc, 32);
        hn = tanhf(acc + p);
        __syncthreads();  // all reads of hs done before overwrite
        if (l < 16) {
            hs[j] = hn;
            out[((long)b * TT + t) * HH + j] = hn;
        }
        __syncthreads();
    }
    if (l < 16) hlast[b * HH + j] = hn;
}

// ---------------------------------------------------------------------------
// K5: logits = act @ fc_w^T + fc_b via f16 MFMA (16x16x32).
// Block tile 64(M) x 128(N), K=128 resident in LDS (no K loop over global).
// 256 threads = 4 waves, each wave computes a 32x64 quadrant (2 m-tiles x
// 4 n-tiles of 16x16). LDS leading dim padded to 136 halfs -> balanced banks.
// A-frag:  A[m=lane&15][k=(lane>>4)*8+j]   (8 contiguous halfs -> b128)
// B-frag:  B[k=(lane>>4)*8+j][n=lane&15] = fc_w[n][k]  (same load pattern)
// D:       D[row=(lane>>4)*4+reg][col=lane&15]
// ---------------------------------------------------------------------------
#define BM 64
#define BN 128
#define LDK 136

__global__ void __launch_bounds__(256) logits_kernel(
        const float* __restrict__ act,   // [8192,128]
        const float* __restrict__ fcw,   // [32000,128]
        const float* __restrict__ fcb,   // [32000]
        float* __restrict__ Cout) {      // [8192,32000]
    __shared__ __align__(16) _Float16 As[BM * LDK];
    __shared__ __align__(16) _Float16 Bs[BN * LDK];
    const int bn = blockIdx.x;
    const int bm = blockIdx.y;
    const int tid = threadIdx.x;

    // Stage A tile: 64 rows x 128 cols f32 -> f16 LDS.
#pragma unroll
    for (int s = 0; s < 8; s++) {
        int f = tid + s * 256;        // [0, 2048)
        int r = f >> 5, c4 = f & 31;  // 32 float4 per row
        float4 v = *(const float4*)(act + ((long)(bm * BM + r)) * HH + c4 * 4);
        _Float16* d = &As[r * LDK + c4 * 4];
        d[0] = (_Float16)v.x; d[1] = (_Float16)v.y;
        d[2] = (_Float16)v.z; d[3] = (_Float16)v.w;
    }
    // Stage B tile: 128 rows x 128 cols.
#pragma unroll
    for (int s = 0; s < 16; s++) {
        int f = tid + s * 256;        // [0, 4096)
        int r = f >> 5, c4 = f & 31;
        float4 v = *(const float4*)(fcw + ((long)(bn * BN + r)) * HH + c4 * 4);
        _Float16* d = &Bs[r * LDK + c4 * 4];
        d[0] = (_Float16)v.x; d[1] = (_Float16)v.y;
        d[2] = (_Float16)v.z; d[3] = (_Float16)v.w;
    }
    __syncthreads();

    const int wv = tid >> 6;
    const int wm = wv >> 1, wn = wv & 1;
    const int r = tid & 15, q = (tid & 63) >> 4;

    floatx4 acc[2][4];
#pragma unroll
    for (int mt = 0; mt < 2; mt++)
#pragma unroll
        for (int nt = 0; nt < 4; nt++) acc[mt][nt] = (floatx4){0.f, 0.f, 0.f, 0.f};

#pragma unroll
    for (int kk = 0; kk < 4; kk++) {
        half8 af[2], bf[4];
#pragma unroll
        for (int mt = 0; mt < 2; mt++)
            af[mt] = *(const half8*)(&As[(wm * 32 + mt * 16 + r) * LDK + kk * 32 + q * 8]);
#pragma unroll
        for (int nt = 0; nt < 4; nt++)
            bf[nt] = *(const half8*)(&Bs[(wn * 64 + nt * 16 + r) * LDK + kk * 32 + q * 8]);
#pragma unroll
        for (int mt = 0; mt < 2; mt++)
#pragma unroll
            for (int nt = 0; nt < 4; nt++)
                acc[mt][nt] = __builtin_amdgcn_mfma_f32_16x16x32_f16(af[mt], bf[nt], acc[mt][nt], 0, 0, 0);
    }

    // Epilogue: D[row=(q*4+r4)][col=r] per 16x16 tile, add bias, store f32.
#pragma unroll
    for (int mt = 0; mt < 2; mt++) {
#pragma unroll
        for (int nt = 0; nt < 4; nt++) {
            int gcol = bn * BN + wn * 64 + nt * 16 + r;
            float bias = fcb[gcol];
#pragma unroll
            for (int r4 = 0; r4 < 4; r4++) {
                int grow = bm * BM + wm * 32 + mt * 16 + q * 4 + r4;
                Cout[(long)grow * VV + gcol] = acc[mt][nt][r4] + bias;
            }
        }
    }
}

// ---------------------------------------------------------------------------
extern "C" void kernel_launch(void* const* d_in, const int* in_sizes, int n_in,
                              void* d_out, int out_size, void* d_ws, size_t ws_size,
                              hipStream_t stream) {
    const int*   x      = (const int*)d_in[0];
    const float* hidden = (const float*)d_in[1];
    const float* emb    = (const float*)d_in[2];
    const float* Wih0   = (const float*)d_in[3];
    const float* Whh0   = (const float*)d_in[4];
    const float* bih0   = (const float*)d_in[5];
    const float* bhh0   = (const float*)d_in[6];
    const float* Wih1   = (const float*)d_in[7];
    const float* Whh1   = (const float*)d_in[8];
    const float* bih1   = (const float*)d_in[9];
    const float* bhh1   = (const float*)d_in[10];
    const float* fcw    = (const float*)d_in[11];
    const float* fcb    = (const float*)d_in[12];

    float* logits = (float*)d_out;
    float* hout   = logits + (long)BB * TT * VV;  // new_hidden [2,B,H]

    float* wsA = (float*)d_ws;            // [B,T,H] pre-activations (4 MB)
    float* ws1 = wsA + (long)BB * TT * HH;  // [B,T,H] layer outputs (4 MB)

    // Layer 0 pre-activations (embedding gather fused).
    preact_kernel<<<BB * TT, HH, 0, stream>>>(emb, x, Wih0, bih0, bhh0, wsA);
    // Layer 0 recurrence.
    rnn_kernel<<<BB, 512, 0, stream>>>(wsA, Whh0, hidden, ws1, hout);
    // Layer 1 pre-activations from layer-0 outputs.
    preact_kernel<<<BB * TT, HH, 0, stream>>>(ws1, nullptr, Wih1, bih1, bhh1, wsA);
    // Layer 1 recurrence (overwrites ws1, its own pre-acts live in wsA).
    rnn_kernel<<<BB, 512, 0, stream>>>(wsA, Whh1, hidden + BB * HH, ws1, hout + BB * HH);
    // Final projection to vocab.
    logits_kernel<<<dim3(VV / BN, (BB * TT) / BM), 256, 0, stream>>>(ws1, fcw, fcb, logits);
}